// Round 1
// baseline (683.524 us; speedup 1.0000x reference)
//
#include <hip/hip_runtime.h>
#include <math.h>

#define NN 50000
#define NE 800000
#define FF 64
#define ZD 192

__device__ __forceinline__ float sigm(float x){ return 1.0f/(1.0f+__expf(-x)); }
__device__ __forceinline__ float sofp(float x){ return fmaxf(x,0.0f)+log1pf(__expf(-fabsf(x))); }
__device__ __forceinline__ float fsilu(float x){ return x/(1.0f+__expf(-x)); }

// ---------------------------------------------------------------------------
// k1: per-node precompute of the node-dependent parts of the gating linears.
//  P2[n][o]      = (Af[n][o], As[n][o])   -- dst (x_i) contributions
//  P2[n][64+o]   = (Bf[n][o], Bs[n][o])   -- src (x_j) contributions
//  Af[n][o] = sum_k atom[n][k] * wf[o][k]        (cols 0:64)
//  Bf[n][o] = sum_k atom[n][k] * wf[o][64+k]     (cols 64:128)
// Also initializes atom_out = atom_fea (k2's atomics accumulate on top).
// ---------------------------------------------------------------------------
__global__ __launch_bounds__(256) void k1_node_pre(
    const float* __restrict__ atom,
    const float* __restrict__ wf, const float* __restrict__ ws,
    float2* __restrict__ P2, float* __restrict__ aout)
{
  __shared__ float4 w4[4096];   // [k][o] : (wfA, wfB, wsA, wsB)  64 KB
  int tid = threadIdx.x;
  for (int i = tid; i < 4096; i += 256) {
    int k = i >> 6, o = i & 63;
    w4[i] = make_float4(wf[o*ZD + k], wf[o*ZD + 64 + k],
                        ws[o*ZD + k], ws[o*ZD + 64 + k]);
  }
  __syncthreads();
  int o  = tid & 63;
  int wid = blockIdx.x * 4 + (tid >> 6);
  int nw  = gridDim.x * 4;
  for (int g = wid; g < NN/4; g += nw) {   // 50000 % 4 == 0
    int n0 = g * 4;
    float x0 = atom[(n0+0)*FF+o], x1 = atom[(n0+1)*FF+o];
    float x2 = atom[(n0+2)*FF+o], x3 = atom[(n0+3)*FF+o];
    aout[(n0+0)*FF+o] = x0; aout[(n0+1)*FF+o] = x1;
    aout[(n0+2)*FF+o] = x2; aout[(n0+3)*FF+o] = x3;
    float4 a0 = {0,0,0,0}, a1 = {0,0,0,0}, a2 = {0,0,0,0}, a3 = {0,0,0,0};
    for (int k = 0; k < 64; k++) {
      float4 w = w4[k*64 + o];
      float y0 = __shfl(x0, k, 64), y1 = __shfl(x1, k, 64);
      float y2 = __shfl(x2, k, 64), y3 = __shfl(x3, k, 64);
      a0.x += w.x*y0; a0.y += w.y*y0; a0.z += w.z*y0; a0.w += w.w*y0;
      a1.x += w.x*y1; a1.y += w.y*y1; a1.z += w.z*y1; a1.w += w.w*y1;
      a2.x += w.x*y2; a2.y += w.y*y2; a2.z += w.z*y2; a2.w += w.w*y2;
      a3.x += w.x*y3; a3.y += w.y*y3; a3.z += w.z*y3; a3.w += w.w*y3;
    }
    P2[(n0+0)*128 +      o] = make_float2(a0.x, a0.z);
    P2[(n0+0)*128 + 64 + o] = make_float2(a0.y, a0.w);
    P2[(n0+1)*128 +      o] = make_float2(a1.x, a1.z);
    P2[(n0+1)*128 + 64 + o] = make_float2(a1.y, a1.w);
    P2[(n0+2)*128 +      o] = make_float2(a2.x, a2.z);
    P2[(n0+2)*128 + 64 + o] = make_float2(a2.y, a2.w);
    P2[(n0+3)*128 +      o] = make_float2(a3.x, a3.z);
    P2[(n0+3)*128 + 64 + o] = make_float2(a3.y, a3.w);
  }
}

// ---------------------------------------------------------------------------
// k2: per-edge message.  8 edges per wave.
//  zf = Af[d] + Bf[s] + WfE@ef + bf ; zs likewise
//  msg = sigmoid(zf)*softplus(zs)*exp(-d^2/18) ; atomicAdd into atom_out[d]
// ---------------------------------------------------------------------------
__global__ __launch_bounds__(256) void k2_msg(
    const int* __restrict__ eidx, const float* __restrict__ efea,
    const float* __restrict__ dist,
    const float* __restrict__ wf, const float* __restrict__ ws,
    const float* __restrict__ bf, const float* __restrict__ bs,
    const float2* __restrict__ P2, float* __restrict__ aout)
{
  __shared__ float2 w2s[4096];   // [k][o] : (wfE, wsE)  32 KB
  __shared__ float  efs[4][512]; // [wave][k*8+ee]        8 KB
  int tid = threadIdx.x;
  for (int i = tid; i < 4096; i += 256) {
    int k = i >> 6, o = i & 63;
    w2s[i] = make_float2(wf[o*ZD + 128 + k], ws[o*ZD + 128 + k]);
  }
  __syncthreads();
  int o  = tid & 63;
  int lw = tid >> 6;
  int ee_st = o >> 3;   // lane/8: which edge this lane stages
  int kk_st = o & 7;
  int wid = blockIdx.x * 4 + lw;
  int nw  = gridDim.x * 4;
  const int ngroups = NE / 8;   // 100000, exact
  for (int g = wid; g < ngroups; g += nw) {
    int e0 = g * 8;
    // stage ef transposed: efs[k*8+ee]; writes land contiguous-permuted (2-way max)
    #pragma unroll
    for (int rep = 0; rep < 8; rep++) {
      int k = rep*8 + kk_st;
      efs[lw][k*8 + ee_st] = efea[(e0 + ee_st)*FF + k];
    }
    float accf[8], accs[8];
    #pragma unroll
    for (int ee = 0; ee < 8; ee++) { accf[ee] = 0.f; accs[ee] = 0.f; }
    for (int k = 0; k < 64; k++) {
      float2 w = w2s[k*64 + o];
      const float4* p4 = reinterpret_cast<const float4*>(&efs[lw][k*8]);
      float4 eA = p4[0], eB = p4[1];   // broadcast reads
      float ev[8] = {eA.x, eA.y, eA.z, eA.w, eB.x, eB.y, eB.z, eB.w};
      #pragma unroll
      for (int ee = 0; ee < 8; ee++) {
        accf[ee] += w.x * ev[ee];
        accs[ee] += w.y * ev[ee];
      }
    }
    float bfo = bf[o], bso = bs[o];
    #pragma unroll
    for (int ee = 0; ee < 8; ee++) {
      int e = e0 + ee;
      int sN = eidx[e], dN = eidx[NE + e];
      float de = dist[e];
      float wd = __expf(-de*de*(1.0f/18.0f));
      float2 vd = P2[dN*128 + o];        // (Af, As)
      float2 vs = P2[sN*128 + 64 + o];   // (Bf, Bs)
      float zf = accf[ee] + vd.x + vs.x + bfo;
      float zs = accs[ee] + vd.y + vs.y + bso;
      float m = sigm(zf) * sofp(zs) * wd;
      atomicAdd(&aout[dN*FF + o], m);
    }
  }
}

// ---------------------------------------------------------------------------
// k3: per-node fc1 partials on the UPDATED node features.
//  C[n*28+j]      (j<14) = sum_k aout[n][k]*fc1[j][k]      (src part)
//  C[n*28+14+j]          = sum_k aout[n][k]*fc1[j][64+k]   (dst part)
// ---------------------------------------------------------------------------
__global__ __launch_bounds__(256) void k3_cpre(
    const float* __restrict__ aout, const float* __restrict__ fc1w,
    float* __restrict__ C)
{
  __shared__ float wT[64*32];  // [k][j], j<28, 8 KB
  __shared__ float xs[4][64];
  int tid = threadIdx.x;
  for (int i = tid; i < 64*28; i += 256) {
    int k = i / 28, j = i % 28;
    wT[k*32 + j] = (j < 14) ? fc1w[j*ZD + k] : fc1w[(j-14)*ZD + 64 + k];
  }
  __syncthreads();
  int o  = tid & 63;
  int lw = tid >> 6;
  int wid = blockIdx.x * 4 + lw;
  int nw  = gridDim.x * 4;
  for (int n = wid; n < NN; n += nw) {
    xs[lw][o] = aout[n*FF + o];
    float acc = 0.f;
    if (o < 28) {
      for (int k = 0; k < 64; k++) acc += xs[lw][k] * wT[k*32 + o];
      C[n*28 + o] = acc;
    }
  }
}

// ---------------------------------------------------------------------------
// k5: edge-update MLP.  8 edges per wave.
//  h[j] = silu(C1[s][j] + C2[d][j] + fc1E@ef + b1[j]),  j<14
//  edge_out[o] = silu(sum_j fc2[o][j]*h[j] + b2[o])
// ---------------------------------------------------------------------------
__global__ __launch_bounds__(256) void k5_edge_mlp(
    const int* __restrict__ eidx, const float* __restrict__ efea,
    const float* __restrict__ fc1w, const float* __restrict__ fc1b,
    const float* __restrict__ fc2w, const float* __restrict__ fc2b,
    const float* __restrict__ C, float* __restrict__ eout)
{
  __shared__ float w1T[64*16];   // [k][j] fc1 edge part, 4 KB
  __shared__ float w2T[14*64];   // [j][o] fc2, 3.5 KB
  __shared__ float efs[4][512];  // 8 KB
  __shared__ float hs[4][128];   // [wave][ee*16+j] 2 KB
  int tid = threadIdx.x;
  for (int i = tid; i < 64*16; i += 256) {
    int k = i >> 4, j = i & 15;
    w1T[i] = (j < 14) ? fc1w[j*ZD + 128 + k] : 0.f;
  }
  for (int i = tid; i < 14*64; i += 256) {
    int j = i >> 6, o = i & 63;
    w2T[i] = fc2w[o*14 + j];
  }
  __syncthreads();
  int o  = tid & 63;
  int lw = tid >> 6;
  int ee_st = o >> 3, kk_st = o & 7;
  int j = o >> 2, q = o & 3;     // (j,q) split: lanes 0..55 cover 14 j's x 4 k-quarters
  int wid = blockIdx.x * 4 + lw;
  int nw  = gridDim.x * 4;
  const int ngroups = NE / 8;
  for (int g = wid; g < ngroups; g += nw) {
    int e0 = g * 8;
    #pragma unroll
    for (int rep = 0; rep < 8; rep++) {
      int k = rep*8 + kk_st;
      efs[lw][k*8 + ee_st] = efea[(e0 + ee_st)*FF + k];
    }
    float p[8];
    #pragma unroll
    for (int ee = 0; ee < 8; ee++) p[ee] = 0.f;
    if (j < 14) {
      #pragma unroll
      for (int kk = 0; kk < 16; kk++) {
        int k = q*16 + kk;
        float w = w1T[k*16 + j];
        const float4* p4 = reinterpret_cast<const float4*>(&efs[lw][k*8]);
        float4 eA = p4[0], eB = p4[1];
        p[0] += w*eA.x; p[1] += w*eA.y; p[2] += w*eA.z; p[3] += w*eA.w;
        p[4] += w*eB.x; p[5] += w*eB.y; p[6] += w*eB.z; p[7] += w*eB.w;
      }
    }
    #pragma unroll
    for (int ee = 0; ee < 8; ee++) {
      p[ee] += __shfl_xor(p[ee], 1, 64);
      p[ee] += __shfl_xor(p[ee], 2, 64);
    }
    if (q == 0 && j < 14) {
      #pragma unroll
      for (int ee = 0; ee < 8; ee++) {
        int e = e0 + ee;
        int sN = eidx[e], dN = eidx[NE + e];
        float h = p[ee] + C[sN*28 + j] + C[dN*28 + 14 + j] + fc1b[j];
        hs[lw][ee*16 + j] = fsilu(h);
      }
    }
    float b2 = fc2b[o];
    #pragma unroll
    for (int ee = 0; ee < 8; ee++) {
      float acc = b2;
      #pragma unroll
      for (int jj = 0; jj < 14; jj++)
        acc += w2T[jj*64 + o] * hs[lw][ee*16 + jj];
      eout[(e0 + ee)*FF + o] = fsilu(acc);
    }
  }
}

// ---------------------------------------------------------------------------
extern "C" void kernel_launch(void* const* d_in, const int* in_sizes, int n_in,
                              void* d_out, int out_size, void* d_ws, size_t ws_size,
                              hipStream_t stream) {
  const float* atom  = (const float*)d_in[0];
  const int*   eidx  = (const int*)  d_in[1];
  const float* efea  = (const float*)d_in[2];
  // d_in[3] = batch (unused), d_in[5] = edge_vec (unused)
  const float* dist  = (const float*)d_in[4];
  const float* wf    = (const float*)d_in[6];
  const float* bf    = (const float*)d_in[7];
  const float* ws    = (const float*)d_in[8];
  const float* bs    = (const float*)d_in[9];
  const float* fc1w  = (const float*)d_in[10];
  const float* fc1b  = (const float*)d_in[11];
  const float* fc2w  = (const float*)d_in[12];
  const float* fc2b  = (const float*)d_in[13];

  float* aout = (float*)d_out;                 // [50000, 64]
  float* eout = aout + (size_t)NN * FF;        // [800000, 64]

  float2* P2 = (float2*)d_ws;                                  // 51.2 MB
  float*  C  = (float*)((char*)d_ws + (size_t)NN * 128 * 8);   // +5.6 MB

  hipLaunchKernelGGL(k1_node_pre, dim3(256), dim3(256), 0, stream,
                     atom, wf, ws, P2, aout);
  hipLaunchKernelGGL(k2_msg, dim3(1024), dim3(256), 0, stream,
                     eidx, efea, dist, wf, ws, bf, bs, P2, aout);
  hipLaunchKernelGGL(k3_cpre, dim3(256), dim3(256), 0, stream,
                     aout, fc1w, C);
  hipLaunchKernelGGL(k5_edge_mlp, dim3(2048), dim3(256), 0, stream,
                     eidx, efea, fc1w, fc1b, fc2w, fc2b, C, eout);
}